// Round 7
// baseline (290.078 us; speedup 1.0000x reference)
//
#include <hip/hip_runtime.h>
#include <math.h>

// ---------------------------------------------------------------------------
// GCN: h1 = relu(Agg(x) @ W1 + b1); h2 = relu(Agg(h1) @ W2 + b2);
//      g = mean-pool(h2, batch); out = relu(g@fc1+b)@fc2+b
// Agg(v)[n] = dinv[n] * ( sum_{e: dst=n} v'[src] + v'[n] ),  v' = v * dinv
// CSR build: bucket sort by dst>>8 (packed 25-bit entries) -> per-bucket LDS
// sortfill (fused with prep). Layer-2 aggregation is CHANNEL-SLICED: h1 is
// stored slice-major h1ps[8][N][8]; blocks with blockIdx&7==s (-> XCD s under
// round-robin dispatch) gather only slice s, so each XCD's random-gather
// working set is 3.2MB and fits its private 4MB L2.
// h2 is never materialized (mm2pool fuses GEMM+relu+mean-pool atomics).
// ---------------------------------------------------------------------------

#define EPB 8192   // edges per block in bucket passes
#define BSH 8      // nodes per bucket = 256
#define NBUK_MAX 512

// --- bucket histogram (LDS-aggregated) ---
__global__ void k_bukhist(const int* __restrict__ dst, int E,
                          int* __restrict__ bkcnt, int nbuk) {
  __shared__ int hist[NBUK_MAX];
  for (int i = threadIdx.x; i < nbuk; i += blockDim.x) hist[i] = 0;
  __syncthreads();
  int i0 = blockIdx.x * EPB, i1 = min(i0 + EPB, E);
  for (int i = i0 + threadIdx.x; i < i1; i += blockDim.x)
    atomicAdd(&hist[dst[i] >> BSH], 1);
  __syncthreads();
  for (int i = threadIdx.x; i < nbuk; i += blockDim.x)
    if (hist[i]) atomicAdd(&bkcnt[i], hist[i]);
}

// 1-block exclusive scan of bucket counts -> bcur (append cursors)
__global__ void k_scan_buk(const int* __restrict__ bkcnt, int* __restrict__ bcur,
                           int nbuk) {
  __shared__ int sh[NBUK_MAX];
  int t = threadIdx.x;
  int v = (t < nbuk) ? bkcnt[t] : 0;
  sh[t] = v;
  __syncthreads();
  for (int o = 1; o < NBUK_MAX; o <<= 1) {
    int u = (t >= o) ? sh[t - o] : 0;
    __syncthreads();
    sh[t] += u;
    __syncthreads();
  }
  if (t < nbuk) bcur[t] = sh[t] - v;  // exclusive
}

// bucket pass: block-aggregated append of packed (src | (dst&255)<<17) into
// bucket-grouped ebuf. After this, bcur[b] == END of bucket b.
__global__ void k_bucket(const int* __restrict__ src, const int* __restrict__ dst,
                         int E, int* __restrict__ bcur, int* __restrict__ ebuf,
                         int nbuk) {
  __shared__ int hist[NBUK_MAX];
  __shared__ int hbase[NBUK_MAX];
  int t = threadIdx.x;
  int i0 = blockIdx.x * EPB, i1 = min(i0 + EPB, E);
  for (int i = t; i < nbuk; i += blockDim.x) hist[i] = 0;
  __syncthreads();
  for (int i = i0 + t; i < i1; i += blockDim.x)
    atomicAdd(&hist[dst[i] >> BSH], 1);
  __syncthreads();
  for (int i = t; i < nbuk; i += blockDim.x) {
    int c = hist[i];
    hbase[i] = c ? atomicAdd(&bcur[i], c) : 0;
  }
  __syncthreads();
  for (int i = t; i < nbuk; i += blockDim.x) hist[i] = 0;
  __syncthreads();
  for (int i = i0 + t; i < i1; i += blockDim.x) {
    int d = dst[i];
    int b = d >> BSH;
    int pos = hbase[b] + atomicAdd(&hist[b], 1);
    ebuf[pos] = src[i] | ((d & 255) << 17);  // src < 2^17
  }
}

// sortfill: one block per bucket. LDS hist -> LDS scan -> row_ptr write ->
// exact-position csr fill via LDS cursors. Fused prep: deg is in hist, so
// dinv + xp (= x*dinv) are produced here too. No global atomics anywhere.
__global__ void __launch_bounds__(256) k_sortfill(
    const int* __restrict__ ebuf, const int* __restrict__ bcur,
    const float* __restrict__ x, int* __restrict__ row_ptr,
    int* __restrict__ csr_src, float* __restrict__ dinv,
    float* __restrict__ xp, int N, int nbuk) {
  __shared__ int hist[256];
  __shared__ int sc[256];
  __shared__ int cur[256];
  int b = blockIdx.x, t = threadIdx.x;
  int e0 = (b == 0) ? 0 : bcur[b - 1];
  int e1 = bcur[b];
  hist[t] = 0;
  __syncthreads();
  for (int i = e0 + t; i < e1; i += 256)
    atomicAdd(&hist[ebuf[i] >> 17], 1);
  __syncthreads();
  int v = hist[t];
  sc[t] = v;
  __syncthreads();
  for (int o = 1; o < 256; o <<= 1) {
    int u = (t >= o) ? sc[t - o] : 0;
    __syncthreads();
    sc[t] += u;
    __syncthreads();
  }
  int excl = sc[t] - v;
  int node = (b << BSH) + t;
  if (node < N) {
    row_ptr[node] = e0 + excl;
    float di = 1.0f / sqrtf((float)(v + 1));  // deg = v; +1 self loop
    dinv[node] = di;
    float4 xv = ((const float4*)x)[node];
    xv.x *= di; xv.y *= di; xv.z *= di; xv.w *= di;
    ((float4*)xp)[node] = xv;
  }
  if (b == nbuk - 1 && t == 0) row_ptr[N] = e1;  // == E
  cur[t] = excl;
  __syncthreads();
  for (int i = e0 + t; i < e1; i += 256) {
    int e = ebuf[i];
    int pos = e0 + atomicAdd(&cur[e >> 17], 1);
    csr_src[pos] = e & 0x1FFFF;
  }
}

// conv1: 4 nodes per wave, 16-lane sub-group per node (mean deg ~16).
// Writes slice-major h1ps[s][n][c] = relu(h1)[n][s*8+c] * dinv[n].
__global__ void k_conv1(const float* __restrict__ xp, const int* __restrict__ row_ptr,
                        const int* __restrict__ csr_src, const float* __restrict__ dinv,
                        const float* __restrict__ W1, const float* __restrict__ b1,
                        float* __restrict__ h1ps, int N) {
  int lane = threadIdx.x & 63;
  int sub = lane >> 4, sl = lane & 15;
  int wid = (blockIdx.x * blockDim.x + threadIdx.x) >> 6;
  int nw = (gridDim.x * blockDim.x) >> 6;
  const float4* x4 = (const float4*)xp;
  float w1 = W1[lane], w2 = W1[64 + lane], w3 = W1[128 + lane], w4 = W1[192 + lane];
  float bb = b1[lane];
  size_t slice_off = (size_t)(lane >> 3) * N * 8 + (lane & 7);
  for (int base = wid * 4; base < N; base += nw * 4) {
    int n = base + sub;
    bool valid = (n < N);
    int e0 = 0, e1 = 0;
    if (valid) { e0 = row_ptr[n]; e1 = row_ptr[n + 1]; }
    float ax = 0.f, ay = 0.f, az = 0.f, aw = 0.f;
    for (int j = e0 + sl; j < e1; j += 16) {
      float4 xs = x4[csr_src[j]];
      ax += xs.x; ay += xs.y; az += xs.z; aw += xs.w;
    }
#pragma unroll
    for (int o = 8; o; o >>= 1) {
      ax += __shfl_xor(ax, o); ay += __shfl_xor(ay, o);
      az += __shfl_xor(az, o); aw += __shfl_xor(aw, o);
    }
    float di = 0.f;
    if (valid) {
      di = dinv[n];
      float4 xn = x4[n];
      ax += xn.x; ay += xn.y; az += xn.z; aw += xn.w;  // self loop
    }
#pragma unroll
    for (int g = 0; g < 4; ++g) {
      int nn = base + g;
      if (nn < N) {
        int srcl = g * 16;
        float bx = __shfl(ax, srcl), by = __shfl(ay, srcl);
        float bz = __shfl(az, srcl), bw = __shfl(aw, srcl);
        float dg = __shfl(di, srcl);
        float o0 = bb;
        o0 = fmaf(bx * dg, w1, o0);
        o0 = fmaf(by * dg, w2, o0);
        o0 = fmaf(bz * dg, w3, o0);
        o0 = fmaf(bw * dg, w4, o0);
        h1ps[slice_off + (size_t)nn * 8] = fmaxf(o0, 0.f) * dg;
      }
    }
  }
}

// agg2s: channel-sliced gather. Block's slice s = blockIdx&7 (-> XCD s under
// round-robin). Wave = 8 sub-groups x 8 lanes; sub-group = 1 node, lane =
// channel in slice. Each XCD's gather working set = h1ps[s] = 3.2MB (L2-fit).
// Writes slice-major aggs[s][n][c] = dinv[n] * (sum + self).
__global__ void __launch_bounds__(256) k_agg2s(
    const float* __restrict__ h1ps, const int* __restrict__ row_ptr,
    const int* __restrict__ csr_src, const float* __restrict__ dinv,
    float* __restrict__ aggs, int N) {
  int s = blockIdx.x & 7;
  int blk = blockIdx.x >> 3;
  int nblk = gridDim.x >> 3;
  const float* __restrict__ hs = h1ps + (size_t)s * N * 8;
  float* __restrict__ as = aggs + (size_t)s * N * 8;
  int lane = threadIdx.x & 63;
  int sub = lane >> 3;   // node within wave-group of 8
  int c = lane & 7;      // channel within slice
  int wv = threadIdx.x >> 6;  // wave in block (4)
  for (int base = blk * 32 + wv * 8; base < N; base += nblk * 32) {
    int n = base + sub;
    if (n < N) {
      int e0 = row_ptr[n], e1 = row_ptr[n + 1];
      float a0 = 0.f, a1 = 0.f, a2 = 0.f, a3 = 0.f;
      int j = e0;
      for (; j + 4 <= e1; j += 4) {
        int s0 = csr_src[j], s1 = csr_src[j + 1];
        int s2 = csr_src[j + 2], s3 = csr_src[j + 3];
        a0 += hs[(size_t)s0 * 8 + c]; a1 += hs[(size_t)s1 * 8 + c];
        a2 += hs[(size_t)s2 * 8 + c]; a3 += hs[(size_t)s3 * 8 + c];
      }
      for (; j < e1; ++j) a0 += hs[(size_t)csr_src[j] * 8 + c];
      float acc = (a0 + a1) + (a2 + a3);
      acc += hs[(size_t)n * 8 + c];  // self loop (pre-scaled)
      as[(size_t)n * 8 + c] = acc * dinv[n];
    }
  }
}

// mm2pool: per block, tile = 32 nodes. h2_tile = relu(agg_tile @ W2 + b2),
// immediately segment-reduced by graph id into gsum atomics (h2 never stored).
// Reads slice-major aggs: per (slice, tile) the 32-node chunk is 1KB contiguous.
__global__ void __launch_bounds__(256, 4) k_mm2pool(
    const float* __restrict__ aggs, const int* __restrict__ batch,
    const float* __restrict__ W2, const float* __restrict__ b2,
    float* __restrict__ gsum, int N) {
  __shared__ float aT[64][36];  // [in_ch][node], pad 36 -> 144B rows
  __shared__ int gid_s[32];
  int tid = threadIdx.x;
  int base = blockIdx.x * 32;
  const float4* a4 = (const float4*)aggs;
  // 8 slices x 32 nodes x 2 float4 = 512 float4s
  for (int idx = tid; idx < 512; idx += 256) {
    int s = idx >> 6;       // slice
    int o = idx & 63;       // float4 within slice-tile
    int node = o >> 1, h4 = o & 1;
    int n = base + node;
    float4 v = make_float4(0.f, 0.f, 0.f, 0.f);
    if (n < N) v = a4[((size_t)s * N + n) * 2 + h4];
    int ch = s * 8 + h4 * 4;
    aT[ch + 0][node] = v.x;
    aT[ch + 1][node] = v.y;
    aT[ch + 2][node] = v.z;
    aT[ch + 3][node] = v.w;
  }
  if (tid < 32) {
    int n = base + tid;
    gid_s[tid] = (n < N) ? batch[n] : -1;
  }
  __syncthreads();
  int c = tid & 127;
  int g = tid >> 7;
  float acc[16];
#pragma unroll
  for (int i = 0; i < 16; ++i) acc[i] = 0.f;
#pragma unroll 4
  for (int k = 0; k < 64; ++k) {
    float w = W2[k * 128 + c];
    const float4* ap = (const float4*)&aT[k][g * 16];
    float4 v0 = ap[0], v1 = ap[1], v2 = ap[2], v3 = ap[3];
    acc[0] = fmaf(v0.x, w, acc[0]);  acc[1] = fmaf(v0.y, w, acc[1]);
    acc[2] = fmaf(v0.z, w, acc[2]);  acc[3] = fmaf(v0.w, w, acc[3]);
    acc[4] = fmaf(v1.x, w, acc[4]);  acc[5] = fmaf(v1.y, w, acc[5]);
    acc[6] = fmaf(v1.z, w, acc[6]);  acc[7] = fmaf(v1.w, w, acc[7]);
    acc[8] = fmaf(v2.x, w, acc[8]);  acc[9] = fmaf(v2.y, w, acc[9]);
    acc[10] = fmaf(v2.z, w, acc[10]); acc[11] = fmaf(v2.w, w, acc[11]);
    acc[12] = fmaf(v3.x, w, acc[12]); acc[13] = fmaf(v3.y, w, acc[13]);
    acc[14] = fmaf(v3.z, w, acc[14]); acc[15] = fmaf(v3.w, w, acc[15]);
  }
  float bias = b2[c];
  float run = 0.f;
  int cur = -1;
#pragma unroll
  for (int i = 0; i < 16; ++i) {
    int n = base + g * 16 + i;
    if (n < N) {
      int gg = gid_s[g * 16 + i];
      float v = fmaxf(acc[i] + bias, 0.f);
      if (gg == cur) {
        run += v;
      } else {
        if (cur >= 0) atomicAdd(&gsum[(size_t)cur * 128 + c], run);
        cur = gg;
        run = v;
      }
    }
  }
  if (cur >= 0) atomicAdd(&gsum[(size_t)cur * 128 + c], run);
}

__device__ __forceinline__ int lower_bound(const int* __restrict__ a, int n, int key) {
  int lo = 0, hi = n;
  while (lo < hi) {
    int m = (lo + hi) >> 1;
    if (a[m] < key) lo = m + 1; else hi = m;
  }
  return lo;
}

// fc head: block per graph. grow = gsum/cnt; out = relu(grow@fc1+b)@fc2+b.
__global__ void k_fc(const float* __restrict__ gsum, const int* __restrict__ batch,
                     const float* __restrict__ fc1W, const float* __restrict__ fc1b,
                     const float* __restrict__ fc2W, const float* __restrict__ fc2b,
                     float* __restrict__ out, int N, int G) {
  int g = blockIdx.x;
  int tid = threadIdx.x;
  __shared__ int bnd[2];
  if (tid == 0) bnd[0] = lower_bound(batch, N, g);
  if (tid == 1) bnd[1] = lower_bound(batch, N, g + 1);
  __shared__ float grow[128];
  __syncthreads();
  int cnt = bnd[1] - bnd[0];
  float inv = 1.0f / (float)max(cnt, 1);
  grow[tid] = gsum[(size_t)g * 128 + tid] * inv;
  __syncthreads();
  if (tid < 64) {
    float o = fc1b[tid];
#pragma unroll 8
    for (int k = 0; k < 128; ++k) o = fmaf(grow[k], fc1W[k * 64 + tid], o);
    o = fmaxf(o, 0.f);
    float v = o * fc2W[tid];
#pragma unroll
    for (int off = 32; off; off >>= 1) v += __shfl_xor(v, off);
    if (tid == 0) out[g] = v + fc2b[0];
  }
}

extern "C" void kernel_launch(void* const* d_in, const int* in_sizes, int n_in,
                              void* d_out, int out_size, void* d_ws, size_t ws_size,
                              hipStream_t stream) {
  const float* x = (const float*)d_in[0];
  const int* ei = (const int*)d_in[1];
  const int* batch = (const int*)d_in[2];
  const float* W1 = (const float*)d_in[3];
  const float* b1 = (const float*)d_in[4];
  const float* W2 = (const float*)d_in[5];
  const float* b2 = (const float*)d_in[6];
  const float* fc1W = (const float*)d_in[7];
  const float* fc1b = (const float*)d_in[8];
  const float* fc2W = (const float*)d_in[9];
  const float* fc2b = (const float*)d_in[10];
  float* out = (float*)d_out;

  int N = in_sizes[0] / 4;   // 100000
  int E = in_sizes[1] / 2;   // 1600000
  int G = out_size;          // 1024
  const int* src = ei;
  const int* dst = ei + E;

  char* ws = (char*)d_ws;
  size_t off = 0;
  auto take = [&](size_t b) {
    char* p = ws + off;
    off += (b + 255) & ~(size_t)255;
    return p;
  };
  int nbuk = (N + 255) >> BSH;        // buckets (391), <= NBUK_MAX
  int ebl = (E + EPB - 1) / EPB;      // bucket-pass blocks (196)
  int* row_ptr  = (int*)take((size_t)(N + 1) * 4);
  int* bkcnt    = (int*)take((size_t)NBUK_MAX * 4);
  int* bcur     = (int*)take((size_t)NBUK_MAX * 4);
  float* dinv   = (float*)take((size_t)N * 4);
  float* xp     = (float*)take((size_t)N * 4 * 4);
  int* ebuf     = (int*)take((size_t)E * 4);
  int* csr_src  = (int*)take((size_t)E * 4);
  float* h1ps   = (float*)take((size_t)N * 64 * 4);
  float* aggs   = (float*)take((size_t)N * 64 * 4);
  float* gsum   = (float*)take((size_t)G * 128 * 4);
  (void)ws_size;

  hipMemsetAsync(bkcnt, 0, (size_t)NBUK_MAX * 4, stream);
  hipMemsetAsync(gsum, 0, (size_t)G * 128 * 4, stream);

  // CSR build: bucket sort (dst>>8) -> per-bucket LDS sortfill (+prep fused)
  k_bukhist<<<ebl, 256, 0, stream>>>(dst, E, bkcnt, nbuk);
  k_scan_buk<<<1, NBUK_MAX, 0, stream>>>(bkcnt, bcur, nbuk);
  k_bucket<<<ebl, 256, 0, stream>>>(src, dst, E, bcur, ebuf, nbuk);
  k_sortfill<<<nbuk, 256, 0, stream>>>(ebuf, bcur, x, row_ptr, csr_src, dinv, xp, N, nbuk);

  // GCN layers + head
  k_conv1<<<2048, 256, 0, stream>>>(xp, row_ptr, csr_src, dinv, W1, b1, h1ps, N);
  int aggblk = ((N + 31) / 32) * 8;  // 8 slices x node-range blocks
  k_agg2s<<<aggblk, 256, 0, stream>>>(h1ps, row_ptr, csr_src, dinv, aggs, N);
  k_mm2pool<<<(N + 31) / 32, 256, 0, stream>>>(aggs, batch, W2, b2, gsum, N);
  k_fc<<<G, 128, 0, stream>>>(gsum, batch, fc1W, fc1b, fc2W, fc2b, out, N, G);
}